// Round 1
// 260.714 us; speedup vs baseline: 1.1065x; 1.1065x over previous
//
#include <hip/hip_runtime.h>

// ESMProjectionHead — f32 in, f32 out. B=64, L=4096, D=128, RL=64, RD=16, DOUT=512
// R8: k1 = unchanged (R7 verified). Epilogue split into 3 high-parallelism kernels:
//     k2a: U-reduce + z=U@Hc  (grid 256 = 64 b x 4 col-quarters, 512KB wts/block)
//     k2b: h=z@W1+b1 raw + per-quarter partial LN stats (no atomics, deterministic)
//     k2c: LN+ReLU from reduced stats, out=h@W2+b2
//     Rationale: old k2_fused ran 64 blocks (25% of CUs), 4MB weights through one
//     CU's L2 port (~27us). Split cuts per-block traffic to <=0.5MB on 256 CUs.

// ---------------- mask-layout detection -----------------------------------
__global__ __launch_bounds__(256) void detect_mask(
    const unsigned int* __restrict__ m, int* __restrict__ flag)
{
    unsigned int v = 0;
    int base = (blockIdx.x * 256 + threadIdx.x) * 4;
#pragma unroll
    for (int i = 0; i < 4; ++i) v |= m[base + i];
    unsigned long long any = __ballot(v > 1u);
    if ((threadIdx.x & 63) == 0 && any) atomicOr(flag, 1);
}

// ---------------- Kernel 1: low-rank projections (f32) --------------------
#define YS_STRIDE 20
#define BCS_CHUNK 516   // 32 ks * 16 cols + 4 pad: chunk q starts at bank 4q
__global__ __launch_bounds__(256, 4) void k1_proj(
    const float* __restrict__ emb,          // [64,4096,128]
    const void* __restrict__ maskp,         // [64,4096] bool (byte or int32)
    const float* __restrict__ Bc,           // [128,16]
    const float* __restrict__ Ac,           // [4096,64]
    float* __restrict__ Part,               // [16][64][1024] f32 partials
    const int* __restrict__ flag)
{
    __shared__ __align__(16) float BcS[4 * BCS_CHUNK];  // 8.1 KB swizzled
    __shared__ __align__(16) float As[64 * 64];         // 16 KB
    __shared__ __align__(16) float Ys[64 * YS_STRIDE];  // 5.1 KB

    const int tid  = threadIdx.x;
    const int lane = tid & 63;
    const int wave = tid >> 6;
    const int q    = tid & 3;               // K-quarter (32 ks)
    const int r    = tid >> 2;              // row within 64-row sub-tile
    const int b    = blockIdx.x >> 4;
    const int c    = blockIdx.x & 15;       // 256-row chunk
    const int byte_mode = *flag;            // block-uniform

    // stage Bc once, swizzled: element (k,col) -> (k>>5)*BCS_CHUNK + (k&31)*16 + col
#pragma unroll
    for (int i = 0; i < 8; ++i) {
        int e = i * 256 + tid;              // [0,2048)
        int k = e >> 4, col = e & 15;
        BcS[(k >> 5) * BCS_CHUNK + (k & 31) * 16 + col] = Bc[e];
    }
    __syncthreads();

    float accU[4] = {0.f, 0.f, 0.f, 0.f};   // U[k=lane][wave*4 .. +3]

    for (int t = 0; t < 4; ++t) {
        const long l0 = (long)c * 256 + t * 64;
        const float* asrc = Ac + l0 * 64;

        // stage A tile 64x64 (16 KB): 4 x float4 per thread
#pragma unroll
        for (int i = 0; i < 4; ++i) {
            int e = (i * 256 + tid) * 4;
            *(float4*)(As + e) = *(const float4*)(asrc + e);
        }

        // ---- X straight to registers: row r, ks q*32..q*32+31 ----
        const float* xrow = emb + ((long)b * 4096 + l0 + r) * 128 + q * 32;
        float4 xv[8];
#pragma unroll
        for (int j = 0; j < 8; ++j) xv[j] = *(const float4*)(xrow + j * 4);

        // ---- y[16] = sum over this thread's 32 ks of x[k]*Bc[k][:] ----
        const float* bq = BcS + q * BCS_CHUNK;   // conflict-free across q now
        float y[16];
#pragma unroll
        for (int j = 0; j < 16; ++j) y[j] = 0.f;
#pragma unroll
        for (int j4 = 0; j4 < 8; ++j4) {
            float4 v = xv[j4];
#pragma unroll
            for (int i = 0; i < 4; ++i) {
                int kk = j4 * 4 + i;        // k within chunk
                float x = (i == 0) ? v.x : (i == 1) ? v.y : (i == 2) ? v.z : v.w;
#pragma unroll
                for (int c4 = 0; c4 < 4; ++c4) {
                    float4 bv = *(const float4*)(bq + kk * 16 + c4 * 4);
                    y[c4 * 4 + 0] += x * bv.x;
                    y[c4 * 4 + 1] += x * bv.y;
                    y[c4 * 4 + 2] += x * bv.z;
                    y[c4 * 4 + 3] += x * bv.w;
                }
            }
        }
        // reduce the 4 K-quarters (register-only)
#pragma unroll
        for (int j = 0; j < 16; ++j) {
            y[j] += __shfl_xor(y[j], 1);
            y[j] += __shfl_xor(y[j], 2);
        }

        long midx = (long)b * 4096 + l0 + r;
        bool mb = byte_mode ? (((const unsigned char*)maskp)[midx] != 0)
                            : (((const int*)maskp)[midx] != 0);
        float mv = mb ? 1.f : 0.f;
        float4 yo;
        if (q == 0)      yo = make_float4(y[0],  y[1],  y[2],  y[3]);
        else if (q == 1) yo = make_float4(y[4],  y[5],  y[6],  y[7]);
        else if (q == 2) yo = make_float4(y[8],  y[9],  y[10], y[11]);
        else             yo = make_float4(y[12], y[13], y[14], y[15]);
        yo.x *= mv; yo.y *= mv; yo.z *= mv; yo.w *= mv;
        *(float4*)(Ys + r * YS_STRIDE + q * 4) = yo;
        __syncthreads();

        // ---- U += A^T @ Y: thread owns k=lane, cols wave*4..+3 ----
        for (int l = 0; l < 64; ++l) {
            float av = As[l * 64 + lane];                                // conflict-free
            float4 yv = *(const float4*)(Ys + l * YS_STRIDE + wave * 4); // bcast
            accU[0] += av * yv.x; accU[1] += av * yv.y;
            accU[2] += av * yv.z; accU[3] += av * yv.w;
        }
        __syncthreads();
    }

    float4 uo = {accU[0], accU[1], accU[2], accU[3]};
    *(float4*)(Part + ((long)(c * 64 + b)) * 1024 + lane * 16 + wave * 4) = uo;
}

// ---------------- Kernel 2a: U-reduce + z = U @ Hc (col-quartered) --------
// grid = 256 blocks: b = blockIdx>>2, jq = blockIdx&3 (128 output cols each)
__global__ __launch_bounds__(256) void k2a(
    const float* __restrict__ Part,         // [16][64][1024]
    const float* __restrict__ Hc,           // [1024,512]
    float* __restrict__ zbuf)               // [64,512]
{
    __shared__ __align__(16) float Us[1024];     // 4 KB
    __shared__ __align__(16) float hp[8][128];   // 4 KB partials

    const int tid = threadIdx.x;            // 256 threads
    const int b   = blockIdx.x >> 2;
    const int jq  = blockIdx.x & 3;

    // ---- U-reduce: thread owns 4 cols of U[1024] ----
    {
        const float* pb = Part + (long)b * 1024 + tid * 4;
        float4 s = {0.f, 0.f, 0.f, 0.f};
#pragma unroll
        for (int cc = 0; cc < 16; ++cc) {
            float4 v = *(const float4*)(pb + (long)cc * 64 * 1024);
            s.x += v.x; s.y += v.y; s.z += v.z; s.w += v.w;
        }
        *(float4*)(Us + tid * 4) = s;
    }
    __syncthreads();

    // ---- z slice: K=1024 split 8-way (128 each), 4 cols/thread ----
    const int c4 = (tid & 31) * 4;          // col within 128-slice
    const int kq = tid >> 5;                // 0..7
    const int k0 = kq * 128;
    float a0 = 0.f, a1 = 0.f, a2 = 0.f, a3 = 0.f;
    for (int k4 = 0; k4 < 128; k4 += 4) {
        float4 u = *(const float4*)(Us + k0 + k4);
        const float* hcp = Hc + (long)(k0 + k4) * 512 + jq * 128 + c4;
        float4 w0  = *(const float4*)(hcp);
        float4 w1v = *(const float4*)(hcp + 512);
        float4 w2v = *(const float4*)(hcp + 1024);
        float4 w3  = *(const float4*)(hcp + 1536);
        a0 += u.x * w0.x + u.y * w1v.x + u.z * w2v.x + u.w * w3.x;
        a1 += u.x * w0.y + u.y * w1v.y + u.z * w2v.y + u.w * w3.y;
        a2 += u.x * w0.z + u.y * w1v.z + u.z * w2v.z + u.w * w3.z;
        a3 += u.x * w0.w + u.y * w1v.w + u.z * w2v.w + u.w * w3.w;
    }
    float4 p = {a0, a1, a2, a3};
    *(float4*)(&hp[kq][c4]) = p;
    __syncthreads();

    if (tid < 128) {
        float z = hp[0][tid] + hp[1][tid] + hp[2][tid] + hp[3][tid]
                + hp[4][tid] + hp[5][tid] + hp[6][tid] + hp[7][tid];
        zbuf[(long)b * 512 + jq * 128 + tid] = z;
    }
}

// ---------------- Kernel 2b: h = z @ W1 + b1 (raw) + partial LN stats -----
__global__ __launch_bounds__(256) void k2b(
    const float* __restrict__ zbuf,         // [64,512]
    const float* __restrict__ W1,           // [512,512]
    const float* __restrict__ b1,
    float* __restrict__ gbuf,               // [64,512] raw h
    float* __restrict__ pstat)              // [64][4][2] partial {sum, sumsq}
{
    __shared__ __align__(16) float zs[512];      // 2 KB
    __shared__ __align__(16) float hp[8][128];   // 4 KB
    __shared__ float red[8];

    const int tid = threadIdx.x;
    const int b   = blockIdx.x >> 2;
    const int jq  = blockIdx.x & 3;

    if (tid < 128)
        *(float4*)(zs + tid * 4) = *(const float4*)(zbuf + (long)b * 512 + tid * 4);
    __syncthreads();

    const int c4 = (tid & 31) * 4;
    const int kq = tid >> 5;
    const int k0 = kq * 64;                 // K=512 split 8-way
    float a0 = 0.f, a1 = 0.f, a2 = 0.f, a3 = 0.f;
    for (int k4 = 0; k4 < 64; k4 += 4) {
        float4 u = *(const float4*)(zs + k0 + k4);
        const float* wp = W1 + (long)(k0 + k4) * 512 + jq * 128 + c4;
        float4 w0  = *(const float4*)(wp);
        float4 w1v = *(const float4*)(wp + 512);
        float4 w2v = *(const float4*)(wp + 1024);
        float4 w3  = *(const float4*)(wp + 1536);
        a0 += u.x * w0.x + u.y * w1v.x + u.z * w2v.x + u.w * w3.x;
        a1 += u.x * w0.y + u.y * w1v.y + u.z * w2v.y + u.w * w3.y;
        a2 += u.x * w0.z + u.y * w1v.z + u.z * w2v.z + u.w * w3.z;
        a3 += u.x * w0.w + u.y * w1v.w + u.z * w2v.w + u.w * w3.w;
    }
    float4 p = {a0, a1, a2, a3};
    *(float4*)(&hp[kq][c4]) = p;
    __syncthreads();

    float s = 0.f, s2 = 0.f;
    if (tid < 128) {
        float hv = hp[0][tid] + hp[1][tid] + hp[2][tid] + hp[3][tid]
                 + hp[4][tid] + hp[5][tid] + hp[6][tid] + hp[7][tid]
                 + b1[jq * 128 + tid];
        gbuf[(long)b * 512 + jq * 128 + tid] = hv;
        s = hv; s2 = hv * hv;
    }
#pragma unroll
    for (int m = 32; m >= 1; m >>= 1) {
        s  += __shfl_xor(s, m);
        s2 += __shfl_xor(s2, m);
    }
    const int wave = tid >> 6, lane = tid & 63;
    if (lane == 0) { red[wave] = s; red[wave + 4] = s2; }
    __syncthreads();
    if (tid == 0) {
        pstat[((long)b * 4 + jq) * 2 + 0] = red[0] + red[1] + red[2] + red[3];
        pstat[((long)b * 4 + jq) * 2 + 1] = red[4] + red[5] + red[6] + red[7];
    }
}

// ---------------- Kernel 2c: LN + ReLU, out = h @ W2 + b2 ------------------
__global__ __launch_bounds__(256) void k2c(
    const float* __restrict__ gbuf,         // [64,512] raw h
    const float* __restrict__ pstat,        // [64][4][2]
    const float* __restrict__ lnw,
    const float* __restrict__ lnb,
    const float* __restrict__ W2,           // [512,512]
    const float* __restrict__ b2,
    float* __restrict__ out)                // [64,512]
{
    __shared__ __align__(16) float hs[512];      // 2 KB (post LN+ReLU)
    __shared__ __align__(16) float hp[8][128];   // 4 KB

    const int tid = threadIdx.x;
    const int b   = blockIdx.x >> 2;
    const int jq  = blockIdx.x & 3;

    float S = 0.f, S2 = 0.f;
#pragma unroll
    for (int qq = 0; qq < 4; ++qq) {
        S  += pstat[((long)b * 4 + qq) * 2 + 0];
        S2 += pstat[((long)b * 4 + qq) * 2 + 1];
    }
    const float mu   = S * (1.f / 512.f);
    const float var  = S2 * (1.f / 512.f) - mu * mu;
    const float rstd = rsqrtf(var + 1e-5f);

    if (tid < 128) {
        float4 g  = *(const float4*)(gbuf + (long)b * 512 + tid * 4);
        float4 w  = *(const float4*)(lnw + tid * 4);
        float4 bb = *(const float4*)(lnb + tid * 4);
        float h0 = (g.x - mu) * rstd * w.x + bb.x;
        float h1 = (g.y - mu) * rstd * w.y + bb.y;
        float h2 = (g.z - mu) * rstd * w.z + bb.z;
        float h3 = (g.w - mu) * rstd * w.w + bb.w;
        h0 = h0 > 0.f ? h0 : 0.f;
        h1 = h1 > 0.f ? h1 : 0.f;
        h2 = h2 > 0.f ? h2 : 0.f;
        h3 = h3 > 0.f ? h3 : 0.f;
        *(float4*)(hs + tid * 4) = make_float4(h0, h1, h2, h3);
    }
    __syncthreads();

    const int c4 = (tid & 31) * 4;
    const int kq = tid >> 5;
    const int k0 = kq * 64;                 // K=512 split 8-way
    float a0 = 0.f, a1 = 0.f, a2 = 0.f, a3 = 0.f;
    for (int k4 = 0; k4 < 64; k4 += 4) {
        float4 u = *(const float4*)(hs + k0 + k4);
        const float* wp = W2 + (long)(k0 + k4) * 512 + jq * 128 + c4;
        float4 w0  = *(const float4*)(wp);
        float4 w1v = *(const float4*)(wp + 512);
        float4 w2v = *(const float4*)(wp + 1024);
        float4 w3  = *(const float4*)(wp + 1536);
        a0 += u.x * w0.x + u.y * w1v.x + u.z * w2v.x + u.w * w3.x;
        a1 += u.x * w0.y + u.y * w1v.y + u.z * w2v.y + u.w * w3.y;
        a2 += u.x * w0.z + u.y * w1v.z + u.z * w2v.z + u.w * w3.z;
        a3 += u.x * w0.w + u.y * w1v.w + u.z * w2v.w + u.w * w3.w;
    }
    float4 p = {a0, a1, a2, a3};
    *(float4*)(&hp[kq][c4]) = p;
    __syncthreads();

    if (tid < 128) {
        float o = hp[0][tid] + hp[1][tid] + hp[2][tid] + hp[3][tid]
                + hp[4][tid] + hp[5][tid] + hp[6][tid] + hp[7][tid]
                + b2[jq * 128 + tid];
        out[(long)b * 512 + jq * 128 + tid] = o;
    }
}

extern "C" void kernel_launch(void* const* d_in, const int* in_sizes, int n_in,
                              void* d_out, int out_size, void* d_ws, size_t ws_size,
                              hipStream_t stream) {
    const float* emb = (const float*)d_in[0];
    const void*  msk = (const void*)d_in[1];
    const float* Bc  = (const float*)d_in[2];
    const float* Ac  = (const float*)d_in[3];
    const float* Hc  = (const float*)d_in[4];
    const float* W1  = (const float*)d_in[5];
    const float* b1  = (const float*)d_in[6];
    const float* lnw = (const float*)d_in[7];
    const float* lnb = (const float*)d_in[8];
    const float* W2  = (const float*)d_in[9];
    const float* b2  = (const float*)d_in[10];

    float* Part  = (float*)d_ws;                                   // 4 MB
    int*   flg   = (int*)((char*)d_ws + 4 * 1024 * 1024);          // 4 B
    float* zbuf  = (float*)((char*)d_ws + 4 * 1024 * 1024 + 4096); // 128 KB
    float* gbuf  = zbuf + 64 * 512;                                // 128 KB
    float* pstat = gbuf + 64 * 512;                                // 2 KB

    hipMemsetAsync(flg, 0, 4, stream);
    detect_mask<<<64, 256, 0, stream>>>((const unsigned int*)msk, flg);
    k1_proj<<<1024, 256, 0, stream>>>(emb, msk, Bc, Ac, Part, flg);
    k2a<<<256, 256, 0, stream>>>(Part, Hc, zbuf);
    k2b<<<256, 256, 0, stream>>>(zbuf, W1, b1, gbuf, pstat);
    k2c<<<256, 256, 0, stream>>>(gbuf, pstat, lnw, lnb, W2, b2, (float*)d_out);
}